// Round 1
// baseline (457.793 us; speedup 1.0000x reference)
//
#include <hip/hip_runtime.h>
#include <hip/hip_bf16.h>

// GNN NNConv, N=25000 nodes, E=50000 edges, C=49 channels, 3 live layers
// (layer 3 of the reference is dead code: JK sum uses xs[0..3] = h + out0..2).
//
// Key factorization: msg[e,o] = sum_k t[e,k]*U_k[src,o] + U_b[src,o]
// where U_k[n,o] = sum_i h[n,i]*W2[k, i*49+o]  (node-level GEMM, not edge-level).

#define NN 25000
#define EE 50000
#define C 49
#define SLOPE 0.01f

__global__ void deg_kernel(const int* __restrict__ ei, float* __restrict__ deg) {
    int e = blockIdx.x * 256 + threadIdx.x;
    if (e < EE) atomicAdd(&deg[ei[EE + e]], 1.0f);
}

// h = leaky_relu(x @ lin_w + lin_b); also initializes JK accumulator (d_out)
__global__ void h_kernel(const float* __restrict__ x, const float* __restrict__ lw,
                         const float* __restrict__ lb, float* __restrict__ hc,
                         float* __restrict__ out) {
    __shared__ float xr[56];
    int n = blockIdx.x, t = threadIdx.x;
    if (t < 56) xr[t] = x[n * 56 + t];
    __syncthreads();
    if (t < C) {
        float acc = lb[t];
#pragma unroll
        for (int i = 0; i < 56; i++) acc += xr[i] * lw[i * C + t];
        acc = acc > 0.f ? acc : SLOPE * acc;
        hc[n * C + t] = acc;
        out[n * C + t] = acc;
    }
}

// per-edge MLP hidden: T[l][e][k] = relu(edge_attr[e] @ W1[l] + b1[l]), 3 layers at once
__global__ void t_kernel(const float* __restrict__ ea, const float* __restrict__ w1,
                         const float* __restrict__ b1, float* __restrict__ T) {
    int e = blockIdx.x * 256 + threadIdx.x;
    if (e >= EE) return;
    float a[10];
#pragma unroll
    for (int j = 0; j < 10; j++) a[j] = ea[e * 10 + j];
#pragma unroll
    for (int l = 0; l < 3; l++) {
#pragma unroll
        for (int k = 0; k < 3; k++) {
            float acc = b1[l * 3 + k];
#pragma unroll
            for (int j = 0; j < 10; j++) acc += a[j] * w1[l * 30 + j * 3 + k];
            T[(l * EE + e) * 3 + k] = fmaxf(acc, 0.f);
        }
    }
}

// U[n, kk*49+c] = sum_i hc[n,i] * Wsel[i*49+c], kk=0..2 from W2, kk=3 from b2
__global__ void u_kernel(const float* __restrict__ hc, const float* __restrict__ w2,
                         const float* __restrict__ b2, float* __restrict__ U) {
    __shared__ float hr[C];
    int n = blockIdx.x, t = threadIdx.x;
    if (t < C) hr[t] = hc[n * C + t];
    __syncthreads();
    if (t < 196) {
        int kk = t / C, c = t % C;
        const float* W = (kk < 3) ? (w2 + kk * 2401) : b2;
        float acc = 0.f;
#pragma unroll
        for (int i = 0; i < C; i++) acc += hr[i] * W[i * C + c];
        U[n * 196 + t] = acc;
    }
}

// wave per edge: gather 4 U-rows of src, combine with t, atomic-scatter to dst
__global__ void edge_kernel(const int* __restrict__ ei, const float* __restrict__ T,
                            const float* __restrict__ U, float* __restrict__ agg) {
    int wid = (blockIdx.x * 256 + threadIdx.x) >> 6;
    int lane = threadIdx.x & 63;
    if (wid >= EE) return;
    int s = ei[wid], d = ei[EE + wid];
    float t0 = T[wid * 3], t1 = T[wid * 3 + 1], t2 = T[wid * 3 + 2];
    if (lane < C) {
        const float* u = U + s * 196;
        float m = t0 * u[lane] + t1 * u[C + lane] + t2 * u[98 + lane] + u[147 + lane];
        atomicAdd(&agg[d * C + lane], m);
    }
}

// out_pre = agg/denom + hc @ root_w + conv_b   (in place on agg)
__global__ void pre_kernel(const float* __restrict__ hc, const float* __restrict__ rw,
                           const float* __restrict__ cb, const float* __restrict__ deg,
                           float* __restrict__ agg) {
    __shared__ float hr[C];
    int n = blockIdx.x, t = threadIdx.x;
    if (t < C) hr[t] = hc[n * C + t];
    __syncthreads();
    if (t < C) {
        float dnm = fmaxf(deg[n], 1.0f);
        float acc = cb[t] + agg[n * C + t] / dnm;
#pragma unroll
        for (int i = 0; i < C; i++) acc += hr[i] * rw[i * C + t];
        agg[n * C + t] = acc;
    }
}

// per-channel sum / sumsq over N rows; threads laid out (g in 0..4, c in 0..48)
__global__ void stats_kernel(const float* __restrict__ pre, float* __restrict__ sums) {
    __shared__ float lsum[245], lsq[245];
    int t = threadIdx.x;
    float s = 0.f, q = 0.f;
    if (t < 245) {
        int g = t / C, c = t % C;
        int rpb = (NN + gridDim.x - 1) / gridDim.x;
        int r0 = blockIdx.x * rpb;
        int r1 = min(r0 + rpb, NN);
        for (int n = r0 + g; n < r1; n += 5) {
            float v = pre[n * C + c];
            s += v; q += v * v;
        }
        lsum[t] = s; lsq[t] = q;
    }
    __syncthreads();
    if (t < C) {
        float S = lsum[t] + lsum[t + 49] + lsum[t + 98] + lsum[t + 147] + lsum[t + 196];
        float Q = lsq[t] + lsq[t + 49] + lsq[t + 98] + lsq[t + 147] + lsq[t + 196];
        atomicAdd(&sums[t], S);
        atomicAdd(&sums[C + t], Q);
    }
}

__global__ void bnfin_kernel(const float* __restrict__ sums, const float* __restrict__ gamma,
                             const float* __restrict__ beta, float* __restrict__ ss) {
    int c = threadIdx.x;
    if (c < C) {
        float inv_n = 1.0f / (float)NN;
        float mu = sums[c] * inv_n;
        float var = sums[C + c] * inv_n - mu * mu;
        float rstd = rsqrtf(var + 1e-5f);
        float sc = rstd * gamma[c];
        ss[c] = sc;
        ss[C + c] = beta[c] - mu * sc;
    }
}

// out = leaky(pre*scale + shift); next-layer hc; JK accumulate into d_out
__global__ void norm_kernel(const float* __restrict__ pre, const float* __restrict__ ss,
                            float* __restrict__ hnext, float* __restrict__ out) {
    int idx = blockIdx.x * 256 + threadIdx.x;
    if (idx >= NN * C) return;
    int c = idx % C;
    float v = pre[idx] * ss[c] + ss[C + c];
    v = v > 0.f ? v : SLOPE * v;
    hnext[idx] = v;
    out[idx] += v;
}

extern "C" void kernel_launch(void* const* d_in, const int* in_sizes, int n_in,
                              void* d_out, int out_size, void* d_ws, size_t ws_size,
                              hipStream_t stream) {
    const float* x     = (const float*)d_in[0];
    const int*   ei    = (const int*)d_in[1];
    const float* ea    = (const float*)d_in[2];
    const float* lin_w = (const float*)d_in[3];
    const float* lin_b = (const float*)d_in[4];
    const float* w1    = (const float*)d_in[5];
    const float* b1    = (const float*)d_in[6];
    const float* w2    = (const float*)d_in[7];
    const float* b2    = (const float*)d_in[8];
    const float* rw    = (const float*)d_in[9];
    const float* cb    = (const float*)d_in[10];
    const float* gm    = (const float*)d_in[11];
    const float* bt    = (const float*)d_in[12];
    float* out = (float*)d_out;

    float* ws   = (float*)d_ws;
    float* deg  = ws;                    // N
    float* hcA  = deg + NN;              // N*49
    float* hcB  = hcA + NN * C;          // N*49
    float* U    = hcB + NN * C;          // N*196
    float* agg  = U + NN * 196;          // N*49 (doubles as out_pre)
    float* T    = agg + NN * C;          // 3*E*3
    float* st   = T + 9 * EE;            // 98 sums + 98 scale/shift

    hipMemsetAsync(deg, 0, NN * sizeof(float), stream);
    deg_kernel<<<(EE + 255) / 256, 256, 0, stream>>>(ei, deg);
    h_kernel<<<NN, 64, 0, stream>>>(x, lin_w, lin_b, hcA, out);
    t_kernel<<<(EE + 255) / 256, 256, 0, stream>>>(ea, w1, b1, T);

    float* cur = hcA;
    float* nxt = hcB;
    for (int l = 0; l < 3; l++) {
        hipMemsetAsync(agg, 0, NN * C * sizeof(float), stream);
        hipMemsetAsync(st, 0, 98 * sizeof(float), stream);
        u_kernel<<<NN, 256, 0, stream>>>(cur, w2 + l * 3 * 2401, b2 + l * 2401, U);
        edge_kernel<<<(EE * 64 + 255) / 256, 256, 0, stream>>>(ei, T + (size_t)l * EE * 3, U, agg);
        pre_kernel<<<NN, 64, 0, stream>>>(cur, rw + l * 2401, cb + l * C, deg, agg);
        stats_kernel<<<128, 256, 0, stream>>>(agg, st);
        bnfin_kernel<<<1, 64, 0, stream>>>(st, gm + l * C, bt + l * C, st + 98);
        norm_kernel<<<(NN * C + 255) / 256, 256, 0, stream>>>(agg, st + 98, nxt, out);
        float* tmp = cur; cur = nxt; nxt = tmp;
    }
}